// Round 11
// baseline (76.477 us; speedup 1.0000x reference)
//
#include <hip/hip_runtime.h>
#include <math.h>

// Problem constants (fixed by setup_inputs)
#define BB 4
#define NIC 64
#define CC 64
#define HH 256
#define WW 256
#define HW (HH * WW)

typedef short sh8 __attribute__((ext_vector_type(8)));    // 8 x bf16 MFMA frag
typedef float f32x4 __attribute__((ext_vector_type(4)));  // MFMA accum

// numpy/jax "reflect" (mirror, edge not repeated), pad=1
__device__ __forceinline__ int refl(int i, int n) {
    i = (i < 0) ? -i : i;
    return (i >= n) ? (2 * n - 2 - i) : i;
}
// fp32 -> bf16 round-to-nearest-even
__device__ __forceinline__ unsigned short f2bf(float v) {
    unsigned int x = __builtin_bit_cast(unsigned int, v);
    return (unsigned short)((x + 0x7FFFu + ((x >> 16) & 1u)) >> 16);
}

// ---- prep kernel: weight A-fragments into d_ws ------------------------------
// wtab[(p*9+s)*64 + lane]: pass p (ni 32p..32p+31), tap s=3*di+dj.
// A-frag (M=taps): lane: row m = lane&15 (taps 9..15 zero), K-elems j=0..7 ->
// ni = 32p + 8*(lane>>4) + j.
__global__ void pff_prep(const float* __restrict__ wgt, uint4* __restrict__ wtab) {
    int e = blockIdx.x * 256 + threadIdx.x;
    if (e >= 1152) return;
    const int c = e >> 6, l = e & 63;
    const int p = c / 9, s = c - p * 9;
    const int tap = l & 15, kg = l >> 4;
    unsigned short h[8];
    #pragma unroll
    for (int j = 0; j < 8; ++j) {
        const int ni = 32 * p + 8 * kg + j;
        const float v = (tap <= 8) ? wgt[tap * 576 + ni * 9 + s] : 0.f;
        h[j] = f2bf(v);
    }
    uint4 o;
    o.x = h[0] | ((unsigned)h[1] << 16);
    o.y = h[2] | ((unsigned)h[3] << 16);
    o.z = h[4] | ((unsigned)h[5] << 16);
    o.w = h[6] | ((unsigned)h[7] << 16);
    wtab[e] = o;
}

// ---- main kernel ------------------------------------------------------------
// Tile 64w x 8h px, 512 threads (8 waves). P1: features staged bf16 into
// [10 rows][66 cols][32 ni] (col-stride 68 B -> bank 17c+nip, conflict-free),
// 2 K-passes; wave wv owns px-row wv, 4 groups of 16 px; 9 taps x 1 MFMA each
// per pass (72 MFMA/wave). Softmax in-reg (R8's verified shuffle). ff -> LDS.
// P2: 4 px rows/thread, 4-way ch-split, wave-private 6-row strips, barrier-free.
__global__ __launch_bounds__(512) void pff_hyb(
    const float* __restrict__ features,
    const float* __restrict__ inpt,
    const float* __restrict__ bias,
    const uint4* __restrict__ wtab,
    float* __restrict__ out)
{
    __shared__ float lds[11220];    // Ftile (bf16 view, 44880 B) ∪ P2 strips
    __shared__ float ffl[9 * 512];  // 18432 B

    const int tid = threadIdx.x;
    const int wv  = __builtin_amdgcn_readfirstlane(tid >> 6);  // 0..7
    const int l   = tid & 63;
    const int pxl = l & 15, kg = l >> 4;
    const int W0 = blockIdx.x * 64, H0 = blockIdx.y * 8, b = blockIdx.z;

    unsigned short* FT = (unsigned short*)lds;

    f32x4 acc[4];
    #pragma unroll
    for (int g = 0; g < 4; ++g) acc[g] = (f32x4){0.f, 0.f, 0.f, 0.f};

    const int bfbase = (wv * 66 + pxl) * 34 + kg * 8;   // short-index B base

    #pragma unroll
    for (int p = 0; p < 2; ++p) {
        // issue weight-frag loads early; consumed after the barrier
        uint4 wf[9];
        #pragma unroll
        for (int s = 0; s < 9; ++s) wf[s] = wtab[(p * 9 + s) * 64 + l];

        // stage pass p: 10560 packed b32 writes (2 bf16 ch per write)
        for (int i = 0; i < 21; ++i) {
            const int flat = tid + 512 * i;
            if (flat < 10560) {
                const int nip = flat / 660;
                const int rc  = flat - nip * 660;
                const int r   = rc / 66, c2 = rc - r * 66;
                const int gr = refl(H0 - 1 + r, HH), gc = refl(W0 - 1 + c2, WW);
                const float* fp = features
                    + ((size_t)b * NIC + 32 * p + 2 * nip) * HW + gr * WW + gc;
                const unsigned pk = f2bf(fp[0]) | ((unsigned)f2bf(fp[HW]) << 16);
                *(unsigned*)&FT[(r * 66 + c2) * 34 + 2 * nip] = pk;
            }
        }
        __syncthreads();   // Ftile pass p ready

        // MFMA: 4 groups x 9 taps (K=32 per call)
        #pragma unroll
        for (int g = 0; g < 4; ++g) {
            #pragma unroll
            for (int s = 0; s < 9; ++s) {
                const int di = s / 3, dj = s - di * 3;
                const unsigned* q =
                    (const unsigned*)&FT[bfbase + (di * 66 + 16 * g + dj) * 34];
                uint4 bw;
                bw.x = q[0]; bw.y = q[1]; bw.z = q[2]; bw.w = q[3];
                acc[g] = __builtin_amdgcn_mfma_f32_16x16x32_bf16(
                    __builtin_bit_cast(sh8, wf[s]),
                    __builtin_bit_cast(sh8, bw), acc[g], 0, 0, 0);
            }
        }
        __syncthreads();   // Ftile reads done (pass 0: before overwrite)
    }

    // ---- softmax per group (taps on lanes pxl+{0,16,32,48}, 2 shfl rounds) --
    float bv4[4];
    #pragma unroll
    for (int j = 0; j < 4; ++j) {
        const int tap = 4 * kg + j;
        bv4[j] = bias[tap <= 8 ? tap : 8];
    }
    #pragma unroll
    for (int g = 0; g < 4; ++g) {
        float lg[4]; bool val[4];
        #pragma unroll
        for (int j = 0; j < 4; ++j) {
            const int tap = 4 * kg + j;
            val[j] = (tap <= 8);
            lg[j] = acc[g][j] + bv4[j];
        }
        float ml = -3e38f;
        #pragma unroll
        for (int j = 0; j < 4; ++j) ml = fmaxf(ml, val[j] ? lg[j] : -3e38f);
        float m = fmaxf(ml, __shfl_xor(ml, 16));
        m = fmaxf(m, __shfl_xor(m, 32));
        float e[4], sl = 0.f;
        #pragma unroll
        for (int j = 0; j < 4; ++j) { e[j] = val[j] ? __expf(lg[j] - m) : 0.f; sl += e[j]; }
        float s = sl + __shfl_xor(sl, 16);
        s += __shfl_xor(s, 32);
        const float inv = 1.f / s;
        #pragma unroll
        for (int j = 0; j < 4; ++j)
            if (val[j]) ffl[(4 * kg + j) * 512 + wv * 64 + 16 * g + pxl] = e[j] * inv;
    }

    // ---- P2 geometry + ch0 prefetch (issued before the barrier: T14) --------
    const int q2 = wv >> 1, tw = wv & 1;
    const int R0 = H0 + 4 * tw;
    int goff[7], loff[7]; bool dm[7];
    #pragma unroll
    for (int t = 0; t < 7; ++t) {
        const int e = l + 64 * t;
        dm[t] = (e < 396);
        const int row = e / 66, col = e - row * 66;
        loff[t] = row * 68 + col;
        goff[t] = refl(R0 - 1 + row, HH) * WW + refl(W0 - 1 + col, WW);
    }
    const float* ip = inpt + ((size_t)b * CC + q2 * 16) * HW;
    float r[7];
    #pragma unroll
    for (int t = 0; t < 7; ++t) r[t] = dm[t] ? ip[goff[t]] : 0.f;

    __syncthreads();   // ffl visible; Ftile dead -> strips may overwrite

    // ffv: per-tap filter values for this thread's 4 px rows
    float ffv[9][4];
    #pragma unroll
    for (int k = 0; k < 9; ++k)
        #pragma unroll
        for (int rr = 0; rr < 4; ++rr)
            ffv[k][rr] = ffl[k * 512 + (4 * tw + rr) * 64 + l];

    float* sb = lds + wv * 816;    // 2 x 408-float wave-private strip bufs
    float* ob = out + ((size_t)b * CC + q2 * 16) * HW;

    for (int ch = 0; ch < 16; ++ch) {
        float* s2 = sb + (ch & 1) * 408;
        #pragma unroll
        for (int t = 0; t < 7; ++t) if (dm[t]) s2[loff[t]] = r[t];
        if (ch < 15) {
            const float* in2 = ip + (size_t)(ch + 1) * HW;
            #pragma unroll
            for (int t = 0; t < 7; ++t) r[t] = dm[t] ? in2[goff[t]] : 0.f;
        }

        float f[3][6];   // [dc][row]
        #pragma unroll
        for (int dc = 0; dc < 3; ++dc)
            #pragma unroll
            for (int row = 0; row < 6; ++row)
                f[dc][row] = s2[row * 68 + l + dc];

        float* op = ob + (size_t)ch * HW + R0 * WW + W0 + l;
        #pragma unroll
        for (int rr = 0; rr < 4; ++rr) {
            float o = ffv[0][rr] * f[0][rr];
            o = fmaf(ffv[1][rr], f[1][rr],     o);
            o = fmaf(ffv[2][rr], f[2][rr],     o);
            o = fmaf(ffv[3][rr], f[0][rr + 1], o);
            o = fmaf(ffv[4][rr], f[1][rr + 1], o);
            o = fmaf(ffv[5][rr], f[2][rr + 1], o);
            o = fmaf(ffv[6][rr], f[0][rr + 2], o);
            o = fmaf(ffv[7][rr], f[1][rr + 2], o);
            o = fmaf(ffv[8][rr], f[2][rr + 2], o);
            op[rr * WW] = o;
        }
    }
}

extern "C" void kernel_launch(void* const* d_in, const int* in_sizes, int n_in,
                              void* d_out, int out_size, void* d_ws, size_t ws_size,
                              hipStream_t stream) {
    const float* features = (const float*)d_in[0];
    const float* inpt     = (const float*)d_in[1];
    const float* wgt      = (const float*)d_in[2];
    const float* bias     = (const float*)d_in[3];
    float* out            = (float*)d_out;
    uint4* wtab           = (uint4*)d_ws;   // 18432 B scratch

    pff_prep<<<dim3(5), dim3(256), 0, stream>>>(wgt, wtab);

    dim3 grid(WW / 64, HH / 8, BB);   // (4, 32, 4) = 512 blocks, 2/CU
    dim3 block(512);
    pff_hyb<<<grid, block, 0, stream>>>(features, inpt, bias, wtab, out);
}